// Round 10
// baseline (351.673 us; speedup 1.0000x reference)
//
#include <hip/hip_runtime.h>
#include <stdint.h>

#define NN 50000
#define EE 800000
#define NROWS 50048  // 782 * 64
#define CB 196       // coarse buckets = ceil(NN/256)
#define CAP 5120     // padded capacity per coarse bucket
#define ACH 4096     // edges per phase-A block

typedef unsigned int u32;
typedef unsigned short u16;
using f32x4 = __attribute__((ext_vector_type(4))) float;
using short8 = __attribute__((ext_vector_type(8))) short;

__device__ __forceinline__ float bflo(u32 u) { return __uint_as_float(u << 16); }
__device__ __forceinline__ float bfhi(u32 u) { return __uint_as_float(u & 0xFFFF0000u); }
__device__ __forceinline__ float bf1(u16 v) { return __uint_as_float(((u32)v) << 16); }
__device__ __forceinline__ u32 f2bf(float f) {
    u32 u = __float_as_uint(f);
    return (u + 0x7FFFu + ((u >> 16) & 1u)) >> 16;
}
__device__ __forceinline__ u32 pack2(float lo, float hi) {
    return f2bf(lo) | (f2bf(hi) << 16);
}

// exclusive scan over 256 threads (one value each)
__device__ __forceinline__ int excl_scan256(int v, int tid) {
    __shared__ int ws_[4];
    int lane = tid & 63, w = tid >> 6;
    int x = v;
    #pragma unroll
    for (int off = 1; off < 64; off <<= 1) {
        int y = __shfl_up(x, off, 64);
        if (lane >= off) x += y;
    }
    if (lane == 63) ws_[w] = x;
    __syncthreads();
    int add = 0;
    if (w > 0) add += ws_[0];
    if (w > 1) add += ws_[1];
    if (w > 2) add += ws_[2];
    return add + x - v;
}

// ---------- dtype detection: flag=1 if inputs are f32, 0 if bf16 ----------

__global__ void detect_kernel(const u32* __restrict__ xw, int* __restrict__ flag) {
    int tid = threadIdx.x;
    int cnt = 0;
    for (int i = tid; i < 8192; i += 256) {
        u32 u = xw[i];
        int e0 = (u >> 7) & 0xFF, e1 = (u >> 23) & 0xFF;
        cnt += (e0 >= 0xC3) + (e1 >= 0xC3);
    }
    #pragma unroll
    for (int off = 32; off; off >>= 1) cnt += __shfl_xor(cnt, off, 64);
    __shared__ int wsum[4];
    if ((tid & 63) == 0) wsum[tid >> 6] = cnt;
    __syncthreads();
    if (tid == 0) flag[0] = (wsum[0] + wsum[1] + wsum[2] + wsum[3] > 100) ? 1 : 0;
}

// ---------- phase A: coarse counting sort by col>>8, clustered writes ----------

__global__ __launch_bounds__(256) void phaseA_kernel(const int* __restrict__ ei,
                                                     int* __restrict__ ccnt,
                                                     u32* __restrict__ cpad) {
    __shared__ int hist[256], lstart[256], lofs[256], gbase[256];
    __shared__ u32 srt[ACH];
    int tid = threadIdx.x;
    int e0 = blockIdx.x * ACH;
    int nv = EE - e0; if (nv > ACH) nv = ACH;
    hist[tid] = 0;
    __syncthreads();
    u32 pk[16];
    int bn[16];
    #pragma unroll
    for (int i = 0; i < 16; i++) {
        int e = e0 + tid + i * 256;
        bn[i] = -1;
        if (e < EE) {
            int r = ei[e], c = ei[EE + e];
            bn[i] = c >> 8;
            pk[i] = (u32)r | ((u32)(c & 255) << 16) | ((u32)bn[i] << 24);
            atomicAdd(&hist[bn[i]], 1);
        }
    }
    __syncthreads();
    int v = hist[tid];
    int excl = excl_scan256(v, tid);
    lstart[tid] = excl;
    lofs[tid] = excl;
    gbase[tid] = atomicAdd(&ccnt[tid], v);
    __syncthreads();
    #pragma unroll
    for (int i = 0; i < 16; i++)
        if (bn[i] >= 0) {
            int lp = atomicAdd(&lofs[bn[i]], 1);
            srt[lp] = pk[i];
        }
    __syncthreads();
    for (int j = tid; j < nv; j += 256) {
        u32 pv = srt[j];
        int b = pv >> 24;
        cpad[(size_t)b * CAP + gbase[b] + (j - lstart[b])] = pv;
    }
}

// exclusive scan of coarse counts -> cbase; sentinels
__global__ void cscan_kernel(const int* __restrict__ ccnt, int* __restrict__ cbase,
                             int* __restrict__ rowptr, float* __restrict__ dinv) {
    int tid = threadIdx.x;
    int v = ccnt[tid];
    int excl = excl_scan256(v, tid);
    cbase[tid] = excl;
    if (tid == 0) {
        rowptr[NN] = EE;
        rowptr[NN + 1] = EE;
        dinv[NN] = 0.f;
    }
}

// ---------- phase B: exact sort within coarse bucket; emits CSR + dinv + rinv ----------

__global__ __launch_bounds__(256) void phaseB_kernel(const u32* __restrict__ cpad,
                                                     const int* __restrict__ ccnt,
                                                     const int* __restrict__ cbase,
                                                     u16* __restrict__ esrc,
                                                     int* __restrict__ rowptr,
                                                     float* __restrict__ dinv,
                                                     float* __restrict__ rinv) {
    __shared__ int hist[256], lstart[256], lofs[256];
    __shared__ u16 srt[CAP];
    int tid = threadIdx.x, cb = blockIdx.x;
    int cnt = ccnt[cb], base = cbase[cb];
    hist[tid] = 0;
    __syncthreads();
    for (int j = tid; j < cnt; j += 256)
        atomicAdd(&hist[(cpad[(size_t)cb * CAP + j] >> 16) & 255], 1);
    __syncthreads();
    int v = hist[tid];
    int excl = excl_scan256(v, tid);
    lstart[tid] = excl;
    lofs[tid] = excl;
    int g = cb * 256 + tid;
    if (g < NN) {
        rowptr[g] = base + excl;
        dinv[g] = v > 0 ? rsqrtf((float)v) : 0.f;
        rinv[g] = v > 0 ? sqrtf((float)v) : 0.f;
    }
    __syncthreads();
    for (int j = tid; j < cnt; j += 256) {
        u32 pv = cpad[(size_t)cb * CAP + j];
        int lp = atomicAdd(&lofs[(pv >> 16) & 255], 1);
        srt[lp] = (u16)(pv & 0xFFFF);
    }
    __syncthreads();
    for (int j = tid; j < cnt; j += 256) esrc[base + j] = srt[j];
}

// ---------- weight prep ----------
// mode 0: chunk J = (k*16 + in/8)*fout + o       (K-concat, ncol=fout)
// mode 1: chunk J = (in/8)*(nk*fout) + k*fout + o (col-concat, ncol=nk*fout)
__global__ void wprep_kernel(const void* __restrict__ w, u16* __restrict__ wt,
                             int fout, int nk, int mode, int total,
                             const int* __restrict__ flag) {
    int idx = blockIdx.x * 256 + threadIdx.x;
    if (idx >= total) return;
    u16 v = flag[0] ? (u16)f2bf(((const float*)w)[idx]) : ((const u16*)w)[idx];
    int per = 128 * fout;
    int k = idx / per, rem = idx % per;
    int in = rem / fout, o = rem % fout;
    size_t J;
    if (mode == 0) J = (size_t)(k * 16 + (in >> 3)) * fout + o;
    else J = (size_t)(in >> 3) * (nk * fout) + k * fout + o;
    wt[J * 8 + (in & 7)] = v;
}

__global__ void bprep_kernel(const void* __restrict__ b1, const void* __restrict__ b2,
                             float* __restrict__ bf, const int* __restrict__ flag) {
    int i = threadIdx.x;  // 192 threads
    if (i < 128) bf[i] = flag[0] ? ((const float*)b1)[i] : bf1(((const u16*)b1)[i]);
    else {
        int j = i - 128;
        bf[i] = flag[0] ? ((const float*)b2)[j] : bf1(((const u16*)b2)[j]);
    }
}

// ---------- scale_x: g0 = dinv .* x (bf16); xb = bf16(x) when f32; zero row NN ----------

__global__ void scalex_kernel(const void* __restrict__ x, u32* __restrict__ g0,
                              u32* __restrict__ xb, const float* __restrict__ dinv,
                              const int* __restrict__ flag) {
    int i = blockIdx.x * 256 + threadIdx.x;
    if (i >= (NN + 1) * 64) return;
    int node = i >> 6;
    int fl = flag[0];
    if (node == NN) {
        g0[i] = 0;
        if (fl) xb[i] = 0;
        return;
    }
    float dv = dinv[node];
    float a, b;
    if (fl) {
        const float* xf = (const float*)x;
        a = xf[2 * i];
        b = xf[2 * i + 1];
        xb[i] = pack2(a, b);
    } else {
        u32 u = ((const u32*)x)[i];
        a = bflo(u);
        b = bfhi(u);
    }
    g0[i] = pack2(a * dv, b * dv);
}

// ---------- propg: g_{k+1} = dinv^2 .* S(g_k), unweighted gather, 128-wide ----------

__global__ __launch_bounds__(256) void propg_kernel(const u32* __restrict__ gin,
                                                    u32* __restrict__ gout,
                                                    const int* __restrict__ rowptr,
                                                    const u16* __restrict__ esrc,
                                                    const float* __restrict__ dinv) {
    int node = (blockIdx.x * 256 + threadIdx.x) >> 6;
    int lane = threadIdx.x & 63;
    if (node > NN) return;
    int e0 = rowptr[node], e1 = rowptr[node + 1];
    float ax = 0.f, ay = 0.f;
    for (int base = e0; base < e1; base += 64) {
        int s_l = NN;  // zero row
        if (base + lane < e1) s_l = esrc[base + lane];
        int cnt = e1 - base;
        if (cnt > 64) cnt = 64;
        for (int j = 0; j < cnt; j += 16) {
            u32 hv[16];
            #pragma unroll
            for (int u = 0; u < 16; u++) {
                int s = __builtin_amdgcn_readlane(s_l, j + u);
                hv[u] = gin[(size_t)s * 64 + lane];
            }
            #pragma unroll
            for (int u = 0; u < 16; u++) {
                ax += bflo(hv[u]);
                ay += bfhi(hv[u]);
            }
        }
    }
    float d = dinv[node];
    float d2 = d * d;
    gout[(size_t)node * 64 + lane] = pack2(ax * d2, ay * d2);
}

// ---------- prop64 (Horner, scaled domain): u_out = dinv.*z + dinv^2.*S(u_in) ----------

__device__ __forceinline__ float gatheru(const u16* __restrict__ uin, int e0, int e1,
                                         int lane, const u16* __restrict__ esrc) {
    float a = 0.f;
    for (int base = e0; base < e1; base += 64) {
        int s_l = NN;
        if (base + lane < e1) s_l = esrc[base + lane];
        int cnt = e1 - base;
        if (cnt > 64) cnt = 64;
        for (int j = 0; j < cnt; j += 16) {
            float hv[16];
            #pragma unroll
            for (int u = 0; u < 16; u++) {
                int s = __builtin_amdgcn_readlane(s_l, j + u);
                hv[u] = bf1(uin[(size_t)s * 64 + lane]);
            }
            #pragma unroll
            for (int u = 0; u < 16; u++) a += hv[u];
        }
    }
    return a;
}

__global__ __launch_bounds__(256) void prop64_add_kernel(const u16* __restrict__ uin,
                                                         const u16* __restrict__ zadd,
                                                         u16* __restrict__ uout,
                                                         const int* __restrict__ rowptr,
                                                         const u16* __restrict__ esrc,
                                                         const float* __restrict__ dinv) {
    int node = (blockIdx.x * 256 + threadIdx.x) >> 6;
    int lane = threadIdx.x & 63;
    if (node > NN) return;
    float s = gatheru(uin, rowptr[node], rowptr[node + 1], lane, esrc);
    float d = dinv[node];
    float r = fmaf(d * d, s, d * bf1(zadd[(size_t)node * 64 + lane]));
    uout[(size_t)node * 64 + lane] = (u16)f2bf(r);
}

__global__ __launch_bounds__(256) void prop64_final_kernel(const u16* __restrict__ uin,
                                                           const u16* __restrict__ z0,
                                                           const float* __restrict__ bias,
                                                           void* __restrict__ outv,
                                                           const int* __restrict__ rowptr,
                                                           const u16* __restrict__ esrc,
                                                           const float* __restrict__ dinv,
                                                           const int* __restrict__ flag) {
    int node = (blockIdx.x * 256 + threadIdx.x) >> 6;
    int lane = threadIdx.x & 63;
    if (node >= NN) return;
    float sg = gatheru(uin, rowptr[node], rowptr[node + 1], lane, esrc);
    float v = dinv[node] * sg + bf1(z0[(size_t)node * 64 + lane]) + bias[lane];
    float m = v;
    #pragma unroll
    for (int off = 32; off; off >>= 1) m = fmaxf(m, __shfl_xor(m, off, 64));
    float e = __expf(v - m);
    float s = e;
    #pragma unroll
    for (int off = 32; off; off >>= 1) s += __shfl_xor(s, off, 64);
    float r = v - m - __logf(s);
    if (flag[0]) ((float*)outv)[(size_t)node * 64 + lane] = r;
    else ((u16*)outv)[(size_t)node * 64 + lane] = (u16)f2bf(r);
}

// ---------- MFMA GEMMs ----------

__device__ __forceinline__ short8 ld8(const u16* p) {
    return __builtin_bit_cast(short8, *(const uint4*)p);
}

// FUSED layer1+Z: H = relu(x@W0 + rinv*(g1@W1+g2@W2+g3@W3) + b1) computed in
// registers, parked in LDS (A-staging layout), then Z = H @ [W2_0..W2_3]
// immediately; H never touches global. Planes -> p0..p3 (plane 3 dinv-scaled).
// Planes must NOT alias any A-input buffer.
__global__ __launch_bounds__(256) void gemm1z_kernel(const u32* __restrict__ a0,
                                                     const u32* __restrict__ a0alt,
                                                     const u32* __restrict__ a1,
                                                     const u32* __restrict__ a2,
                                                     const u32* __restrict__ a3,
                                                     const u16* __restrict__ wt1,
                                                     const u16* __restrict__ wt2,
                                                     const float* __restrict__ rinv,
                                                     const float* __restrict__ dinv,
                                                     const float* __restrict__ bias,
                                                     u16* __restrict__ p0, u16* __restrict__ p1,
                                                     u16* __restrict__ p2, u16* __restrict__ p3,
                                                     const int* __restrict__ flag) {
    __shared__ uint4 hs[1024];
    const u32* A0 = flag[0] ? a0alt : a0;
    const u32* bufs[4] = {A0, a1, a2, a3};
    int t = threadIdx.x;
    int lane = t & 63, w = t >> 6;
    int row0 = blockIdx.x * 64;
    int m = lane & 15, qo = lane >> 4;
    f32x4 accx[8], accg[8];
    #pragma unroll
    for (int tt = 0; tt < 8; tt++) {
        accx[tt] = (f32x4){0.f, 0.f, 0.f, 0.f};
        accg[tt] = (f32x4){0.f, 0.f, 0.f, 0.f};
    }

    uint4 p[4];
    {
        const uint4* src = (const uint4*)A0 + (size_t)row0 * 16;
        #pragma unroll
        for (int i = 0; i < 4; i++) p[i] = src[t + 256 * i];
    }
    #pragma unroll
    for (int hop = 0; hop < 4; hop++) {
        __syncthreads();
        #pragma unroll
        for (int i = 0; i < 4; i++) {
            int g = t + 256 * i;
            hs[(g >> 4) * 16 + ((g & 15) ^ ((g >> 4) & 15))] = p[i];
        }
        __syncthreads();
        if (hop + 1 < 4) {
            const uint4* src = (const uint4*)bufs[hop + 1] + (size_t)row0 * 16;
            #pragma unroll
            for (int i = 0; i < 4; i++) p[i] = src[t + 256 * i];
        }
        #pragma unroll
        for (int q = 0; q < 4; q++) {
            short8 a = __builtin_bit_cast(short8,
                hs[(16 * w + m) * 16 + ((q * 4 + qo) ^ m)]);
            short8 b[8];
            #pragma unroll
            for (int tt = 0; tt < 8; tt++)
                b[tt] = ld8(wt1 + ((size_t)(hop * 16 + q * 4 + qo) * 128 + 16 * tt + m) * 8);
            if (hop == 0) {
                #pragma unroll
                for (int tt = 0; tt < 8; tt++)
                    accx[tt] = __builtin_amdgcn_mfma_f32_16x16x32_bf16(a, b[tt], accx[tt], 0, 0, 0);
            } else {
                #pragma unroll
                for (int tt = 0; tt < 8; tt++)
                    accg[tt] = __builtin_amdgcn_mfma_f32_16x16x32_bf16(a, b[tt], accg[tt], 0, 0, 0);
            }
        }
    }

    int r0 = row0 + 16 * w + qo * 4;
    float rv[4], scp3[4];
    #pragma unroll
    for (int r = 0; r < 4; r++) {
        int rr = r0 + r;
        rv[r] = (rr < NN) ? rinv[rr] : 0.f;
        scp3[r] = (rr < NN) ? dinv[rr] : 0.f;
    }
    __syncthreads();  // all A-staging reads done; reuse hs for H tile
    u16* lds16 = (u16*)hs;
    // park relu'd H tile in A-staging layout
    #pragma unroll
    for (int tt = 0; tt < 8; tt++) {
        float bs = bias[16 * tt + m];
        #pragma unroll
        for (int r = 0; r < 4; r++) {
            int rr = r0 + r;
            float vv = 0.f;
            if (rr < NN) vv = fmaxf(accx[tt][r] + rv[r] * accg[tt][r] + bs, 0.f);
            int lrow = 16 * w + qo * 4 + r;
            int col = 16 * tt + m;
            lds16[lrow * 128 + (((col >> 3) ^ (lrow & 15)) << 3) + (col & 7)] = (u16)f2bf(vv);
        }
    }
    __syncthreads();
    // Z phase: [64x128] @ [128x256] from LDS A-frags
    f32x4 az[4][4];
    #pragma unroll
    for (int py = 0; py < 4; py++)
        #pragma unroll
        for (int tt = 0; tt < 4; tt++) az[py][tt] = (f32x4){0.f, 0.f, 0.f, 0.f};
    #pragma unroll
    for (int q = 0; q < 4; q++) {
        short8 a = __builtin_bit_cast(short8,
            hs[(16 * w + m) * 16 + ((q * 4 + qo) ^ m)]);
        #pragma unroll
        for (int py = 0; py < 4; py++) {
            #pragma unroll
            for (int tt = 0; tt < 4; tt++) {
                short8 b = ld8(wt2 + ((size_t)(q * 4 + qo) * 256 + py * 64 + 16 * tt + m) * 8);
                az[py][tt] = __builtin_amdgcn_mfma_f32_16x16x32_bf16(a, b, az[py][tt], 0, 0, 0);
            }
        }
    }
    // plane epilogues via LDS transpose -> full-line uint4 stores
    u16* planes[4] = {p0, p1, p2, p3};
    #pragma unroll
    for (int py = 0; py < 4; py++) {
        __syncthreads();
        #pragma unroll
        for (int tt = 0; tt < 4; tt++) {
            #pragma unroll
            for (int r = 0; r < 4; r++) {
                int rr = r0 + r;
                float sc = (rr < NN) ? ((py == 3) ? scp3[r] : 1.f) : 0.f;
                lds16[(16 * w + qo * 4 + r) * 64 + 16 * tt + m] = (u16)f2bf(sc * az[py][tt][r]);
            }
        }
        __syncthreads();
        uint4* zp4 = (uint4*)planes[py];
        const uint4* epi4 = (const uint4*)hs;
        #pragma unroll
        for (int i = 0; i < 2; i++) {
            int g = t + 256 * i;
            int row = g >> 3, ch = g & 7;
            zp4[(size_t)(row0 + row) * 8 + ch] = epi4[g];
        }
    }
}

// UNFUSED fallback: layer-1 GEMM only, in-place (block-local rows), LDS epilogue
__global__ __launch_bounds__(256) void gemm1_kernel(const u32* __restrict__ a0,
                                                    const u32* __restrict__ a0alt,
                                                    const u32* __restrict__ a1,
                                                    const u32* __restrict__ a2,
                                                    const u32* __restrict__ a3,
                                                    const u16* __restrict__ wt,
                                                    const float* __restrict__ rinv,
                                                    const float* __restrict__ bias,
                                                    u32* __restrict__ outH,
                                                    const int* __restrict__ flag) {
    __shared__ uint4 hs[1024];
    const u32* A0 = flag[0] ? a0alt : a0;
    const u32* bufs[4] = {A0, a1, a2, a3};
    int t = threadIdx.x;
    int lane = t & 63, w = t >> 6;
    int row0 = blockIdx.x * 64;
    int m = lane & 15, qo = lane >> 4;
    f32x4 accx[8], accg[8];
    #pragma unroll
    for (int tt = 0; tt < 8; tt++) {
        accx[tt] = (f32x4){0.f, 0.f, 0.f, 0.f};
        accg[tt] = (f32x4){0.f, 0.f, 0.f, 0.f};
    }
    uint4 p[4];
    {
        const uint4* src = (const uint4*)A0 + (size_t)row0 * 16;
        #pragma unroll
        for (int i = 0; i < 4; i++) p[i] = src[t + 256 * i];
    }
    #pragma unroll
    for (int hop = 0; hop < 4; hop++) {
        __syncthreads();
        #pragma unroll
        for (int i = 0; i < 4; i++) {
            int g = t + 256 * i;
            hs[(g >> 4) * 16 + ((g & 15) ^ ((g >> 4) & 15))] = p[i];
        }
        __syncthreads();
        if (hop + 1 < 4) {
            const uint4* src = (const uint4*)bufs[hop + 1] + (size_t)row0 * 16;
            #pragma unroll
            for (int i = 0; i < 4; i++) p[i] = src[t + 256 * i];
        }
        #pragma unroll
        for (int q = 0; q < 4; q++) {
            short8 a = __builtin_bit_cast(short8,
                hs[(16 * w + m) * 16 + ((q * 4 + qo) ^ m)]);
            short8 b[8];
            #pragma unroll
            for (int tt = 0; tt < 8; tt++)
                b[tt] = ld8(wt + ((size_t)(hop * 16 + q * 4 + qo) * 128 + 16 * tt + m) * 8);
            if (hop == 0) {
                #pragma unroll
                for (int tt = 0; tt < 8; tt++)
                    accx[tt] = __builtin_amdgcn_mfma_f32_16x16x32_bf16(a, b[tt], accx[tt], 0, 0, 0);
            } else {
                #pragma unroll
                for (int tt = 0; tt < 8; tt++)
                    accg[tt] = __builtin_amdgcn_mfma_f32_16x16x32_bf16(a, b[tt], accg[tt], 0, 0, 0);
            }
        }
    }
    int r0 = row0 + 16 * w + qo * 4;
    float rv[4];
    #pragma unroll
    for (int r = 0; r < 4; r++) rv[r] = (r0 + r < NN) ? rinv[r0 + r] : 0.f;
    __syncthreads();
    u16* lds16 = (u16*)hs;
    #pragma unroll
    for (int tt = 0; tt < 8; tt++) {
        float bs = bias[16 * tt + m];
        #pragma unroll
        for (int r = 0; r < 4; r++) {
            int rr = r0 + r;
            float vv = 0.f;
            if (rr < NN) vv = fmaxf(accx[tt][r] + rv[r] * accg[tt][r] + bs, 0.f);
            lds16[(16 * w + qo * 4 + r) * 128 + 16 * tt + m] = (u16)f2bf(vv);
        }
    }
    __syncthreads();
    uint4* out4 = (uint4*)outH;
    const uint4* epi4 = (const uint4*)hs;
    #pragma unroll
    for (int i = 0; i < 4; i++) {
        int g = t + 256 * i;
        int row = g >> 4, ch = g & 15;
        out4[(size_t)(row0 + row) * 16 + ch] = epi4[g];
    }
}

// UNFUSED fallback: Z planes from H (LDS transpose epilogue)
__global__ __launch_bounds__(256) void gemmz_kernel(const u32* __restrict__ aH,
                                                    const u16* __restrict__ wt,
                                                    const float* __restrict__ dinv,
                                                    u16* __restrict__ p0, u16* __restrict__ p1,
                                                    u16* __restrict__ p2, u16* __restrict__ p3) {
    __shared__ uint4 hs[1024];
    int t = threadIdx.x;
    int lane = t & 63, w = t >> 6;
    int row0 = blockIdx.x * 64;
    int py = blockIdx.y;
    int cb = py * 64;
    int m = lane & 15, qo = lane >> 4;
    f32x4 acc[4];
    #pragma unroll
    for (int tt = 0; tt < 4; tt++) acc[tt] = (f32x4){0.f, 0.f, 0.f, 0.f};
    {
        const uint4* src = (const uint4*)aH + (size_t)row0 * 16;
        #pragma unroll
        for (int i = 0; i < 4; i++) {
            int g = t + 256 * i;
            hs[(g >> 4) * 16 + ((g & 15) ^ ((g >> 4) & 15))] = src[g];
        }
    }
    __syncthreads();
    #pragma unroll
    for (int q = 0; q < 4; q++) {
        short8 a = __builtin_bit_cast(short8,
            hs[(16 * w + m) * 16 + ((q * 4 + qo) ^ m)]);
        short8 b[4];
        #pragma unroll
        for (int tt = 0; tt < 4; tt++)
            b[tt] = ld8(wt + ((size_t)(q * 4 + qo) * 256 + cb + 16 * tt + m) * 8);
        #pragma unroll
        for (int tt = 0; tt < 4; tt++)
            acc[tt] = __builtin_amdgcn_mfma_f32_16x16x32_bf16(a, b[tt], acc[tt], 0, 0, 0);
    }
    u16* zp = (py == 0) ? p0 : (py == 1) ? p1 : (py == 2) ? p2 : p3;
    int r0 = row0 + 16 * w + qo * 4;
    float sc[4];
    #pragma unroll
    for (int r = 0; r < 4; r++) {
        int rr = r0 + r;
        sc[r] = (rr < NN) ? ((py == 3) ? dinv[rr] : 1.f) : 0.f;
    }
    __syncthreads();
    u16* lds16 = (u16*)hs;
    #pragma unroll
    for (int tt = 0; tt < 4; tt++) {
        #pragma unroll
        for (int r = 0; r < 4; r++) {
            lds16[(16 * w + qo * 4 + r) * 64 + 16 * tt + m] = (u16)f2bf(sc[r] * acc[tt][r]);
        }
    }
    __syncthreads();
    uint4* zp4 = (uint4*)zp;
    const uint4* epi4 = (const uint4*)hs;
    #pragma unroll
    for (int i = 0; i < 2; i++) {
        int g = t + 256 * i;
        int row = g >> 3, ch = g & 7;
        zp4[(size_t)(row0 + row) * 8 + ch] = epi4[g];
    }
}

// ---------- launch ----------

extern "C" void kernel_launch(void* const* d_in, const int* in_sizes, int n_in,
                              void* d_out, int out_size, void* d_ws, size_t ws_size,
                              hipStream_t stream) {
    const void* x  = d_in[0];
    const int*  ei = (const int*)d_in[1];
    const void* W1 = d_in[2];
    const void* b1 = d_in[3];
    const void* W2 = d_in[4];
    const void* b2 = d_in[5];

    char* ws = (char*)d_ws;
    size_t p = 0;
    auto alloc = [&](size_t bytes) -> void* {
        void* r = ws + p;
        p = (p + bytes + 255) & ~(size_t)255;
        return r;
    };
    int*   flag   = (int*)  alloc(256);
    int*   rowptr = (int*)  alloc((size_t)(NN + 2) * 4);
    float* dinv   = (float*)alloc((size_t)(NN + 64) * 4);
    float* rinv   = (float*)alloc((size_t)(NN + 64) * 4);
    int*   ccnt   = (int*)  alloc(256 * 4);
    int*   cbase  = (int*)  alloc(256 * 4);
    u16*   esrc   = (u16*)  alloc((size_t)EE * 2);
    u16*   wt1    = (u16*)  alloc((size_t)64 * 128 * 16);   // 128 KB
    u16*   wt2    = (u16*)  alloc((size_t)16 * 256 * 16);   // 64 KB
    float* biasF  = (float*)alloc(192 * 4);
    const size_t hbytes = (size_t)(NROWS + 16) * 64 * 4;
    u32* X = (u32*)alloc(hbytes);   // xb (flag=1); cpad aliases; unfused Horner scratch
    u32* P = (u32*)alloc(hbytes);   // g0 -> g3
    u32* Q = (u32*)alloc(hbytes);   // g1 -> (unfused) H / (fused) Horner scratch
    u32* R = (u32*)alloc(hbytes);   // g2
    // base ~= 53.6 MB. Fused path needs 2 extra plane buffers (+25.6 MB).
    int fused = (p + 2 * hbytes + 256 <= ws_size) ? 1 : 0;
    u32* H5 = fused ? (u32*)alloc(hbytes) : nullptr;
    u32* H6 = fused ? (u32*)alloc(hbytes) : nullptr;
    u32* cpad = X;

    const size_t ZP = (size_t)(NROWS + 16) * 64;  // u16 elements per plane

    hipMemsetAsync(ccnt, 0, 256 * 4, stream);
    detect_kernel<<<1, 256, 0, stream>>>((const u32*)x, flag);
    phaseA_kernel<<<(EE + ACH - 1) / ACH, 256, 0, stream>>>(ei, ccnt, cpad);
    cscan_kernel<<<1, 256, 0, stream>>>(ccnt, cbase, rowptr, dinv);
    phaseB_kernel<<<CB, 256, 0, stream>>>(cpad, ccnt, cbase, esrc, rowptr, dinv, rinv);
    wprep_kernel<<<(4 * 128 * 128 + 255) / 256, 256, 0, stream>>>(
        W1, wt1, 128, 4, 0, 4 * 128 * 128, flag);
    wprep_kernel<<<(4 * 128 * 64 + 255) / 256, 256, 0, stream>>>(
        W2, wt2, 64, 4, 1, 4 * 128 * 64, flag);
    bprep_kernel<<<1, 192, 0, stream>>>(b1, b2, biasF, flag);

    const int PGX = ((NN + 1) * 64 + 255) / 256;  // 12501 (covers zero row NN)
    const int PGF = (NN * 64) / 256;              // 12500
    const int GG = NROWS / 64;                    // 782

    scalex_kernel<<<PGX, 256, 0, stream>>>(x, P, X, dinv, flag);

    // layer 1: g_k chain (unweighted gathers)
    propg_kernel<<<PGX, 256, 0, stream>>>(P, Q, rowptr, esrc, dinv);  // g1
    propg_kernel<<<PGX, 256, 0, stream>>>(Q, R, rowptr, esrc, dinv);  // g2
    propg_kernel<<<PGX, 256, 0, stream>>>(R, P, rowptr, esrc, dinv);  // g3 (g0 dead)

    if (fused) {
        u16* z0 = (u16*)H5;
        u16* z1 = (u16*)H5 + ZP;
        u16* z2 = (u16*)H6;
        u16* u3 = (u16*)H6 + ZP;   // dinv.*z3
        u16* uQ0 = (u16*)Q;        // Q dead after gemm1z
        u16* uQ1 = (u16*)Q + ZP;
        gemm1z_kernel<<<GG, 256, 0, stream>>>(
            (const u32*)x, X, Q, R, P, wt1, wt2, rinv, dinv, biasF,
            z0, z1, z2, u3, flag);
        prop64_add_kernel<<<PGX, 256, 0, stream>>>(u3, z2, uQ0, rowptr, esrc, dinv);
        prop64_add_kernel<<<PGX, 256, 0, stream>>>(uQ0, z1, uQ1, rowptr, esrc, dinv);
        prop64_final_kernel<<<PGF, 256, 0, stream>>>(uQ1, z0, biasF + 128, d_out,
                                                     rowptr, esrc, dinv, flag);
    } else {
        u16* zR0 = (u16*)R;        // z0 (R dead after gemm1)
        u16* zR1 = (u16*)R + ZP;   // z1
        u16* zP0 = (u16*)P;        // z2 (later u_w2)
        u16* zP1 = (u16*)P + ZP;   // u3
        u16* uX0 = (u16*)X;        // u_w1
        gemm1_kernel<<<GG, 256, 0, stream>>>(
            (const u32*)x, X, Q, R, P, wt1, rinv, biasF, Q, flag);
        gemmz_kernel<<<dim3(GG, 4), 256, 0, stream>>>(Q, wt2, dinv, zR0, zR1, zP0, zP1);
        prop64_add_kernel<<<PGX, 256, 0, stream>>>(zP1, zP0, uX0, rowptr, esrc, dinv);
        prop64_add_kernel<<<PGX, 256, 0, stream>>>(uX0, zR1, zP0, rowptr, esrc, dinv);
        prop64_final_kernel<<<PGF, 256, 0, stream>>>(zP0, zR0, biasF + 128, d_out,
                                                     rowptr, esrc, dinv, flag);
    }
}

// Round 11
// 335.452 us; speedup vs baseline: 1.0484x; 1.0484x over previous
//
#include <hip/hip_runtime.h>
#include <stdint.h>

#define NN 50000
#define EE 800000
#define NROWS 50048  // 782 * 64
#define CB 196       // coarse buckets = ceil(NN/256)
#define CAP 5120     // padded capacity per coarse bucket
#define ACH 4096     // edges per phase-A block

typedef unsigned int u32;
typedef unsigned short u16;
using f32x4 = __attribute__((ext_vector_type(4))) float;
using short8 = __attribute__((ext_vector_type(8))) short;

__device__ __forceinline__ float bflo(u32 u) { return __uint_as_float(u << 16); }
__device__ __forceinline__ float bfhi(u32 u) { return __uint_as_float(u & 0xFFFF0000u); }
__device__ __forceinline__ float bf1(u16 v) { return __uint_as_float(((u32)v) << 16); }
__device__ __forceinline__ u32 f2bf(float f) {
    u32 u = __float_as_uint(f);
    return (u + 0x7FFFu + ((u >> 16) & 1u)) >> 16;
}
__device__ __forceinline__ u32 pack2(float lo, float hi) {
    return f2bf(lo) | (f2bf(hi) << 16);
}

// exclusive scan over 256 threads (one value each)
__device__ __forceinline__ int excl_scan256(int v, int tid) {
    __shared__ int ws_[4];
    int lane = tid & 63, w = tid >> 6;
    int x = v;
    #pragma unroll
    for (int off = 1; off < 64; off <<= 1) {
        int y = __shfl_up(x, off, 64);
        if (lane >= off) x += y;
    }
    if (lane == 63) ws_[w] = x;
    __syncthreads();
    int add = 0;
    if (w > 0) add += ws_[0];
    if (w > 1) add += ws_[1];
    if (w > 2) add += ws_[2];
    return add + x - v;
}

// ---------- dtype detection: flag=1 if inputs are f32, 0 if bf16 ----------

__global__ void detect_kernel(const u32* __restrict__ xw, int* __restrict__ flag) {
    int tid = threadIdx.x;
    int cnt = 0;
    for (int i = tid; i < 8192; i += 256) {
        u32 u = xw[i];
        int e0 = (u >> 7) & 0xFF, e1 = (u >> 23) & 0xFF;
        cnt += (e0 >= 0xC3) + (e1 >= 0xC3);
    }
    #pragma unroll
    for (int off = 32; off; off >>= 1) cnt += __shfl_xor(cnt, off, 64);
    __shared__ int wsum[4];
    if ((tid & 63) == 0) wsum[tid >> 6] = cnt;
    __syncthreads();
    if (tid == 0) flag[0] = (wsum[0] + wsum[1] + wsum[2] + wsum[3] > 100) ? 1 : 0;
}

// ---------- phase A: coarse counting sort by col>>8, clustered writes ----------

__global__ __launch_bounds__(256) void phaseA_kernel(const int* __restrict__ ei,
                                                     int* __restrict__ ccnt,
                                                     u32* __restrict__ cpad) {
    __shared__ int hist[256], lstart[256], lofs[256], gbase[256];
    __shared__ u32 srt[ACH];
    int tid = threadIdx.x;
    int e0 = blockIdx.x * ACH;
    int nv = EE - e0; if (nv > ACH) nv = ACH;
    hist[tid] = 0;
    __syncthreads();
    u32 pk[16];
    int bn[16];
    #pragma unroll
    for (int i = 0; i < 16; i++) {
        int e = e0 + tid + i * 256;
        bn[i] = -1;
        if (e < EE) {
            int r = ei[e], c = ei[EE + e];
            bn[i] = c >> 8;
            pk[i] = (u32)r | ((u32)(c & 255) << 16) | ((u32)bn[i] << 24);
            atomicAdd(&hist[bn[i]], 1);
        }
    }
    __syncthreads();
    int v = hist[tid];
    int excl = excl_scan256(v, tid);
    lstart[tid] = excl;
    lofs[tid] = excl;
    gbase[tid] = atomicAdd(&ccnt[tid], v);
    __syncthreads();
    #pragma unroll
    for (int i = 0; i < 16; i++)
        if (bn[i] >= 0) {
            int lp = atomicAdd(&lofs[bn[i]], 1);
            srt[lp] = pk[i];
        }
    __syncthreads();
    for (int j = tid; j < nv; j += 256) {
        u32 pv = srt[j];
        int b = pv >> 24;
        cpad[(size_t)b * CAP + gbase[b] + (j - lstart[b])] = pv;
    }
}

// exclusive scan of coarse counts -> cbase; sentinels
__global__ void cscan_kernel(const int* __restrict__ ccnt, int* __restrict__ cbase,
                             int* __restrict__ rowptr, float* __restrict__ dinv) {
    int tid = threadIdx.x;
    int v = ccnt[tid];
    int excl = excl_scan256(v, tid);
    cbase[tid] = excl;
    if (tid == 0) {
        rowptr[NN] = EE;
        rowptr[NN + 1] = EE;
        dinv[NN] = 0.f;
    }
}

// ---------- phase B: exact sort within coarse bucket; emits CSR + dinv + rinv ----------

__global__ __launch_bounds__(256) void phaseB_kernel(const u32* __restrict__ cpad,
                                                     const int* __restrict__ ccnt,
                                                     const int* __restrict__ cbase,
                                                     u16* __restrict__ esrc,
                                                     int* __restrict__ rowptr,
                                                     float* __restrict__ dinv,
                                                     float* __restrict__ rinv) {
    __shared__ int hist[256], lstart[256], lofs[256];
    __shared__ u16 srt[CAP];
    int tid = threadIdx.x, cb = blockIdx.x;
    int cnt = ccnt[cb], base = cbase[cb];
    hist[tid] = 0;
    __syncthreads();
    for (int j = tid; j < cnt; j += 256)
        atomicAdd(&hist[(cpad[(size_t)cb * CAP + j] >> 16) & 255], 1);
    __syncthreads();
    int v = hist[tid];
    int excl = excl_scan256(v, tid);
    lstart[tid] = excl;
    lofs[tid] = excl;
    int g = cb * 256 + tid;
    if (g < NN) {
        rowptr[g] = base + excl;
        dinv[g] = v > 0 ? rsqrtf((float)v) : 0.f;
        rinv[g] = v > 0 ? sqrtf((float)v) : 0.f;
    }
    __syncthreads();
    for (int j = tid; j < cnt; j += 256) {
        u32 pv = cpad[(size_t)cb * CAP + j];
        int lp = atomicAdd(&lofs[(pv >> 16) & 255], 1);
        srt[lp] = (u16)(pv & 0xFFFF);
    }
    __syncthreads();
    for (int j = tid; j < cnt; j += 256) esrc[base + j] = srt[j];
}

// ---------- weight prep ----------
// mode 0: chunk J = (k*16 + in/8)*fout + o       (K-concat, ncol=fout)
// mode 1: chunk J = (in/8)*(nk*fout) + k*fout + o (col-concat, ncol=nk*fout)
__global__ void wprep_kernel(const void* __restrict__ w, u16* __restrict__ wt,
                             int fout, int nk, int mode, int total,
                             const int* __restrict__ flag) {
    int idx = blockIdx.x * 256 + threadIdx.x;
    if (idx >= total) return;
    u16 v = flag[0] ? (u16)f2bf(((const float*)w)[idx]) : ((const u16*)w)[idx];
    int per = 128 * fout;
    int k = idx / per, rem = idx % per;
    int in = rem / fout, o = rem % fout;
    size_t J;
    if (mode == 0) J = (size_t)(k * 16 + (in >> 3)) * fout + o;
    else J = (size_t)(in >> 3) * (nk * fout) + k * fout + o;
    wt[J * 8 + (in & 7)] = v;
}

__global__ void bprep_kernel(const void* __restrict__ b1, const void* __restrict__ b2,
                             float* __restrict__ bf, const int* __restrict__ flag) {
    int i = threadIdx.x;  // 192 threads
    if (i < 128) bf[i] = flag[0] ? ((const float*)b1)[i] : bf1(((const u16*)b1)[i]);
    else {
        int j = i - 128;
        bf[i] = flag[0] ? ((const float*)b2)[j] : bf1(((const u16*)b2)[j]);
    }
}

// ---------- scale_x: g0 = dinv .* x (bf16); xb = bf16(x) when f32; zero row NN ----------

__global__ void scalex_kernel(const void* __restrict__ x, u32* __restrict__ g0,
                              u32* __restrict__ xb, const float* __restrict__ dinv,
                              const int* __restrict__ flag) {
    int i = blockIdx.x * 256 + threadIdx.x;
    if (i >= (NN + 1) * 64) return;
    int node = i >> 6;
    int fl = flag[0];
    if (node == NN) {
        g0[i] = 0;
        if (fl) xb[i] = 0;
        return;
    }
    float dv = dinv[node];
    float a, b;
    if (fl) {
        const float* xf = (const float*)x;
        a = xf[2 * i];
        b = xf[2 * i + 1];
        xb[i] = pack2(a, b);
    } else {
        u32 u = ((const u32*)x)[i];
        a = bflo(u);
        b = bfhi(u);
    }
    g0[i] = pack2(a * dv, b * dv);
}

// ---------- propg: g_{k+1} = dinv^2 .* S(g_k), unweighted gather, 128-wide ----------

__global__ __launch_bounds__(256) void propg_kernel(const u32* __restrict__ gin,
                                                    u32* __restrict__ gout,
                                                    const int* __restrict__ rowptr,
                                                    const u16* __restrict__ esrc,
                                                    const float* __restrict__ dinv) {
    int node = (blockIdx.x * 256 + threadIdx.x) >> 6;
    int lane = threadIdx.x & 63;
    if (node > NN) return;
    int e0 = rowptr[node], e1 = rowptr[node + 1];
    float ax = 0.f, ay = 0.f;
    for (int base = e0; base < e1; base += 64) {
        int s_l = NN;  // zero row
        if (base + lane < e1) s_l = esrc[base + lane];
        int cnt = e1 - base;
        if (cnt > 64) cnt = 64;
        for (int j = 0; j < cnt; j += 16) {
            u32 hv[16];
            #pragma unroll
            for (int u = 0; u < 16; u++) {
                int s = __builtin_amdgcn_readlane(s_l, j + u);
                hv[u] = gin[(size_t)s * 64 + lane];
            }
            #pragma unroll
            for (int u = 0; u < 16; u++) {
                ax += bflo(hv[u]);
                ay += bfhi(hv[u]);
            }
        }
    }
    float d = dinv[node];
    float d2 = d * d;
    gout[(size_t)node * 64 + lane] = pack2(ax * d2, ay * d2);
}

// ---------- prop64 (Horner, scaled domain): u_out = dinv.*z + dinv^2.*S(u_in) ----------

__device__ __forceinline__ float gatheru(const u16* __restrict__ uin, int e0, int e1,
                                         int lane, const u16* __restrict__ esrc) {
    float a = 0.f;
    for (int base = e0; base < e1; base += 64) {
        int s_l = NN;
        if (base + lane < e1) s_l = esrc[base + lane];
        int cnt = e1 - base;
        if (cnt > 64) cnt = 64;
        for (int j = 0; j < cnt; j += 16) {
            float hv[16];
            #pragma unroll
            for (int u = 0; u < 16; u++) {
                int s = __builtin_amdgcn_readlane(s_l, j + u);
                hv[u] = bf1(uin[(size_t)s * 64 + lane]);
            }
            #pragma unroll
            for (int u = 0; u < 16; u++) a += hv[u];
        }
    }
    return a;
}

__global__ __launch_bounds__(256) void prop64_add_kernel(const u16* __restrict__ uin,
                                                         const u16* __restrict__ zadd,
                                                         u16* __restrict__ uout,
                                                         const int* __restrict__ rowptr,
                                                         const u16* __restrict__ esrc,
                                                         const float* __restrict__ dinv) {
    int node = (blockIdx.x * 256 + threadIdx.x) >> 6;
    int lane = threadIdx.x & 63;
    if (node > NN) return;
    float s = gatheru(uin, rowptr[node], rowptr[node + 1], lane, esrc);
    float d = dinv[node];
    float r = fmaf(d * d, s, d * bf1(zadd[(size_t)node * 64 + lane]));
    uout[(size_t)node * 64 + lane] = (u16)f2bf(r);
}

__global__ __launch_bounds__(256) void prop64_final_kernel(const u16* __restrict__ uin,
                                                           const u16* __restrict__ z0,
                                                           const float* __restrict__ bias,
                                                           void* __restrict__ outv,
                                                           const int* __restrict__ rowptr,
                                                           const u16* __restrict__ esrc,
                                                           const float* __restrict__ dinv,
                                                           const int* __restrict__ flag) {
    int node = (blockIdx.x * 256 + threadIdx.x) >> 6;
    int lane = threadIdx.x & 63;
    if (node >= NN) return;
    float sg = gatheru(uin, rowptr[node], rowptr[node + 1], lane, esrc);
    float v = dinv[node] * sg + bf1(z0[(size_t)node * 64 + lane]) + bias[lane];
    float m = v;
    #pragma unroll
    for (int off = 32; off; off >>= 1) m = fmaxf(m, __shfl_xor(m, off, 64));
    float e = __expf(v - m);
    float s = e;
    #pragma unroll
    for (int off = 32; off; off >>= 1) s += __shfl_xor(s, off, 64);
    float r = v - m - __logf(s);
    if (flag[0]) ((float*)outv)[(size_t)node * 64 + lane] = r;
    else ((u16*)outv)[(size_t)node * 64 + lane] = (u16)f2bf(r);
}

// ---------- MFMA GEMMs ----------

__device__ __forceinline__ short8 ld8(const u16* p) {
    return __builtin_bit_cast(short8, *(const uint4*)p);
}

// layer 1: H = relu(x@W0 + rinv*(g1@W1+g2@W2+g3@W3) + b1) -> bf16 [N,128], in-place OK
// (block-local rows). Epilogue: shfl-paired u32 LDS writes (stride 68 words,
// conflict-free) -> full-line uint4 global stores.
__global__ __launch_bounds__(256) void gemm1_kernel(const u32* __restrict__ a0,
                                                    const u32* __restrict__ a0alt,
                                                    const u32* __restrict__ a1,
                                                    const u32* __restrict__ a2,
                                                    const u32* __restrict__ a3,
                                                    const u16* __restrict__ wt,
                                                    const float* __restrict__ rinv,
                                                    const float* __restrict__ bias,
                                                    u32* __restrict__ outH,
                                                    const int* __restrict__ flag) {
    __shared__ uint4 hs[1088];  // 16 KB A-staging + epilogue pad (64 rows x 68 words)
    const u32* A0 = flag[0] ? a0alt : a0;
    const u32* bufs[4] = {A0, a1, a2, a3};
    int t = threadIdx.x;
    int lane = t & 63, w = t >> 6;
    int row0 = blockIdx.x * 64;
    int m = lane & 15, qo = lane >> 4;
    f32x4 accx[8], accg[8];
    #pragma unroll
    for (int tt = 0; tt < 8; tt++) {
        accx[tt] = (f32x4){0.f, 0.f, 0.f, 0.f};
        accg[tt] = (f32x4){0.f, 0.f, 0.f, 0.f};
    }
    uint4 p[4];
    {
        const uint4* src = (const uint4*)A0 + (size_t)row0 * 16;
        #pragma unroll
        for (int i = 0; i < 4; i++) p[i] = src[t + 256 * i];
    }
    #pragma unroll
    for (int hop = 0; hop < 4; hop++) {
        __syncthreads();
        #pragma unroll
        for (int i = 0; i < 4; i++) {
            int g = t + 256 * i;
            hs[(g >> 4) * 16 + ((g & 15) ^ ((g >> 4) & 15))] = p[i];
        }
        __syncthreads();
        if (hop + 1 < 4) {
            const uint4* src = (const uint4*)bufs[hop + 1] + (size_t)row0 * 16;
            #pragma unroll
            for (int i = 0; i < 4; i++) p[i] = src[t + 256 * i];
        }
        #pragma unroll
        for (int q = 0; q < 4; q++) {
            short8 a = __builtin_bit_cast(short8,
                hs[(16 * w + m) * 16 + ((q * 4 + qo) ^ m)]);
            short8 b[8];
            #pragma unroll
            for (int tt = 0; tt < 8; tt++)
                b[tt] = ld8(wt + ((size_t)(hop * 16 + q * 4 + qo) * 128 + 16 * tt + m) * 8);
            if (hop == 0) {
                #pragma unroll
                for (int tt = 0; tt < 8; tt++)
                    accx[tt] = __builtin_amdgcn_mfma_f32_16x16x32_bf16(a, b[tt], accx[tt], 0, 0, 0);
            } else {
                #pragma unroll
                for (int tt = 0; tt < 8; tt++)
                    accg[tt] = __builtin_amdgcn_mfma_f32_16x16x32_bf16(a, b[tt], accg[tt], 0, 0, 0);
            }
        }
    }
    int r0 = row0 + 16 * w + qo * 4;
    float rv[4];
    #pragma unroll
    for (int r = 0; r < 4; r++) rv[r] = (r0 + r < NN) ? rinv[r0 + r] : 0.f;
    __syncthreads();  // A-staging reads done; reuse hs
    u32* lds32 = (u32*)hs;
    int lrowb = 16 * w + qo * 4;
    #pragma unroll
    for (int tt = 0; tt < 8; tt++) {
        float bs = bias[16 * tt + m];
        #pragma unroll
        for (int r = 0; r < 4; r++) {
            int rr = r0 + r;
            float vv = 0.f;
            if (rr < NN) vv = fmaxf(accx[tt][r] + rv[r] * accg[tt][r] + bs, 0.f);
            u32 vb = f2bf(vv);
            u32 ob = (u32)__shfl_xor((int)vb, 1, 64);
            if (!(m & 1))
                lds32[(lrowb + r) * 68 + 8 * tt + (m >> 1)] = vb | (ob << 16);
        }
    }
    __syncthreads();
    uint4* out4 = (uint4*)outH;  // output row = 128 u16 = 16 uint4
    #pragma unroll
    for (int i = 0; i < 4; i++) {
        int g = t + 256 * i;
        int row = g >> 4, ch = g & 15;
        out4[(size_t)(row0 + row) * 16 + ch] = *(const uint4*)&lds32[row * 68 + ch * 4];
    }
}

// layer 2: Z planes = H @ [W2_0|W2_1|W2_2|W2_3]; plane 3 dinv-scaled, row NN zeroed.
// Same conflict-free LDS epilogue (stride 36 words).
__global__ __launch_bounds__(256) void gemmz_kernel(const u32* __restrict__ aH,
                                                    const u16* __restrict__ wt,
                                                    const float* __restrict__ dinv,
                                                    u16* __restrict__ p0, u16* __restrict__ p1,
                                                    u16* __restrict__ p2, u16* __restrict__ p3) {
    __shared__ uint4 hs[1024];
    int t = threadIdx.x;
    int lane = t & 63, w = t >> 6;
    int row0 = blockIdx.x * 64;
    int py = blockIdx.y;
    int cb = py * 64;
    int m = lane & 15, qo = lane >> 4;
    f32x4 acc[4];
    #pragma unroll
    for (int tt = 0; tt < 4; tt++) acc[tt] = (f32x4){0.f, 0.f, 0.f, 0.f};
    {
        const uint4* src = (const uint4*)aH + (size_t)row0 * 16;
        #pragma unroll
        for (int i = 0; i < 4; i++) {
            int g = t + 256 * i;
            hs[(g >> 4) * 16 + ((g & 15) ^ ((g >> 4) & 15))] = src[g];
        }
    }
    __syncthreads();
    #pragma unroll
    for (int q = 0; q < 4; q++) {
        short8 a = __builtin_bit_cast(short8,
            hs[(16 * w + m) * 16 + ((q * 4 + qo) ^ m)]);
        short8 b[4];
        #pragma unroll
        for (int tt = 0; tt < 4; tt++)
            b[tt] = ld8(wt + ((size_t)(q * 4 + qo) * 256 + cb + 16 * tt + m) * 8);
        #pragma unroll
        for (int tt = 0; tt < 4; tt++)
            acc[tt] = __builtin_amdgcn_mfma_f32_16x16x32_bf16(a, b[tt], acc[tt], 0, 0, 0);
    }
    u16* zp = (py == 0) ? p0 : (py == 1) ? p1 : (py == 2) ? p2 : p3;
    int r0 = row0 + 16 * w + qo * 4;
    float sc[4];
    #pragma unroll
    for (int r = 0; r < 4; r++) {
        int rr = r0 + r;
        sc[r] = (rr < NN) ? ((py == 3) ? dinv[rr] : 1.f) : 0.f;
    }
    __syncthreads();
    u32* lds32 = (u32*)hs;
    int lrowb = 16 * w + qo * 4;
    #pragma unroll
    for (int tt = 0; tt < 4; tt++) {
        #pragma unroll
        for (int r = 0; r < 4; r++) {
            u32 vb = f2bf(sc[r] * acc[tt][r]);
            u32 ob = (u32)__shfl_xor((int)vb, 1, 64);
            if (!(m & 1))
                lds32[(lrowb + r) * 36 + 8 * tt + (m >> 1)] = vb | (ob << 16);
        }
    }
    __syncthreads();
    uint4* zp4 = (uint4*)zp;  // plane row = 64 u16 = 8 uint4
    #pragma unroll
    for (int i = 0; i < 2; i++) {
        int g = t + 256 * i;
        int row = g >> 3, ch = g & 7;
        zp4[(size_t)(row0 + row) * 8 + ch] = *(const uint4*)&lds32[row * 36 + ch * 4];
    }
}

// ---------- launch ----------

extern "C" void kernel_launch(void* const* d_in, const int* in_sizes, int n_in,
                              void* d_out, int out_size, void* d_ws, size_t ws_size,
                              hipStream_t stream) {
    const void* x  = d_in[0];
    const int*  ei = (const int*)d_in[1];
    const void* W1 = d_in[2];
    const void* b1 = d_in[3];
    const void* W2 = d_in[4];
    const void* b2 = d_in[5];

    char* ws = (char*)d_ws;
    size_t p = 0;
    auto alloc = [&](size_t bytes) -> void* {
        void* r = ws + p;
        p = (p + bytes + 255) & ~(size_t)255;
        return r;
    };
    int*   flag   = (int*)  alloc(256);
    int*   rowptr = (int*)  alloc((size_t)(NN + 2) * 4);
    float* dinv   = (float*)alloc((size_t)(NN + 64) * 4);
    float* rinv   = (float*)alloc((size_t)(NN + 64) * 4);
    int*   ccnt   = (int*)  alloc(256 * 4);
    int*   cbase  = (int*)  alloc(256 * 4);
    u16*   esrc   = (u16*)  alloc((size_t)EE * 2);
    u16*   wt1    = (u16*)  alloc((size_t)64 * 128 * 16);   // 128 KB
    u16*   wt2    = (u16*)  alloc((size_t)16 * 256 * 16);   // 64 KB
    float* biasF  = (float*)alloc(192 * 4);
    const size_t hbytes = (size_t)(NROWS + 16) * 64 * 4;
    u32* X = (u32*)alloc(hbytes);   // xb (flag=1); cpad aliases; Horner scratch
    u32* P = (u32*)alloc(hbytes);   // g0 -> g3 -> z2/u3 planes
    u32* Q = (u32*)alloc(hbytes);   // g1 -> H (in-place)
    u32* R = (u32*)alloc(hbytes);   // g2 -> z0/z1 planes
    // total ~= 53.6 MB
    u32* cpad = X;

    const size_t ZP = (size_t)(NROWS + 16) * 64;  // u16 elements per plane
    u16* zR0 = (u16*)R;        // z0 (R dead after gemm1)
    u16* zR1 = (u16*)R + ZP;   // z1
    u16* zP0 = (u16*)P;        // z2 (later u_w2)
    u16* zP1 = (u16*)P + ZP;   // u3 = dinv.*z3
    u16* uX0 = (u16*)X;        // u_w1

    hipMemsetAsync(ccnt, 0, 256 * 4, stream);
    detect_kernel<<<1, 256, 0, stream>>>((const u32*)x, flag);
    phaseA_kernel<<<(EE + ACH - 1) / ACH, 256, 0, stream>>>(ei, ccnt, cpad);
    cscan_kernel<<<1, 256, 0, stream>>>(ccnt, cbase, rowptr, dinv);
    phaseB_kernel<<<CB, 256, 0, stream>>>(cpad, ccnt, cbase, esrc, rowptr, dinv, rinv);
    wprep_kernel<<<(4 * 128 * 128 + 255) / 256, 256, 0, stream>>>(
        W1, wt1, 128, 4, 0, 4 * 128 * 128, flag);
    wprep_kernel<<<(4 * 128 * 64 + 255) / 256, 256, 0, stream>>>(
        W2, wt2, 64, 4, 1, 4 * 128 * 64, flag);
    bprep_kernel<<<1, 192, 0, stream>>>(b1, b2, biasF, flag);

    const int PGX = ((NN + 1) * 64 + 255) / 256;  // 12501 (covers zero row NN)
    const int PGF = (NN * 64) / 256;              // 12500
    const int GG = NROWS / 64;                    // 782

    scalex_kernel<<<PGX, 256, 0, stream>>>(x, P, X, dinv, flag);

    // layer 1: g_k chain (unweighted gathers), dual-acc GEMM + bias + relu -> H (=Q)
    propg_kernel<<<PGX, 256, 0, stream>>>(P, Q, rowptr, esrc, dinv);  // g1
    propg_kernel<<<PGX, 256, 0, stream>>>(Q, R, rowptr, esrc, dinv);  // g2
    propg_kernel<<<PGX, 256, 0, stream>>>(R, P, rowptr, esrc, dinv);  // g3 (g0 dead)
    gemm1_kernel<<<GG, 256, 0, stream>>>(
        (const u32*)x, X, Q, R, P, wt1, rinv, biasF, Q, flag);

    // layer 2: Z planes from H; Horner in scaled domain; fused bias + log_softmax
    gemmz_kernel<<<dim3(GG, 4), 256, 0, stream>>>(Q, wt2, dinv, zR0, zR1, zP0, zP1);
    prop64_add_kernel<<<PGX, 256, 0, stream>>>(zP1, zP0, uX0, rowptr, esrc, dinv);   // u_w1
    prop64_add_kernel<<<PGX, 256, 0, stream>>>(uX0, zR1, zP0, rowptr, esrc, dinv);   // u_w2
    prop64_final_kernel<<<PGF, 256, 0, stream>>>(zP0, zR0, biasF + 128, d_out,
                                                 rowptr, esrc, dinv, flag);
}

// Round 12
// 333.359 us; speedup vs baseline: 1.0549x; 1.0063x over previous
//
#include <hip/hip_runtime.h>
#include <stdint.h>

#define NN 50000
#define EE 800000
#define NROWS 50048  // 782 * 64
#define CB 196       // coarse buckets = ceil(NN/256)
#define CAP 5120     // padded capacity per coarse bucket
#define ACH 4096     // edges per phase-A block

typedef unsigned int u32;
typedef unsigned short u16;
using f32x4 = __attribute__((ext_vector_type(4))) float;
using short8 = __attribute__((ext_vector_type(8))) short;

__device__ __forceinline__ float bflo(u32 u) { return __uint_as_float(u << 16); }
__device__ __forceinline__ float bfhi(u32 u) { return __uint_as_float(u & 0xFFFF0000u); }
__device__ __forceinline__ float bf1(u16 v) { return __uint_as_float(((u32)v) << 16); }
__device__ __forceinline__ u32 f2bf(float f) {
    u32 u = __float_as_uint(f);
    return (u + 0x7FFFu + ((u >> 16) & 1u)) >> 16;
}
__device__ __forceinline__ u32 pack2(float lo, float hi) {
    return f2bf(lo) | (f2bf(hi) << 16);
}

// exclusive scan over 256 threads (one value each)
__device__ __forceinline__ int excl_scan256(int v, int tid) {
    __shared__ int ws_[4];
    int lane = tid & 63, w = tid >> 6;
    int x = v;
    #pragma unroll
    for (int off = 1; off < 64; off <<= 1) {
        int y = __shfl_up(x, off, 64);
        if (lane >= off) x += y;
    }
    if (lane == 63) ws_[w] = x;
    __syncthreads();
    int add = 0;
    if (w > 0) add += ws_[0];
    if (w > 1) add += ws_[1];
    if (w > 2) add += ws_[2];
    return add + x - v;
}

// ---------- dtype detection: flag=1 if inputs are f32, 0 if bf16 ----------

__global__ void detect_kernel(const u32* __restrict__ xw, int* __restrict__ flag) {
    int tid = threadIdx.x;
    int cnt = 0;
    for (int i = tid; i < 8192; i += 256) {
        u32 u = xw[i];
        int e0 = (u >> 7) & 0xFF, e1 = (u >> 23) & 0xFF;
        cnt += (e0 >= 0xC3) + (e1 >= 0xC3);
    }
    #pragma unroll
    for (int off = 32; off; off >>= 1) cnt += __shfl_xor(cnt, off, 64);
    __shared__ int wsum[4];
    if ((tid & 63) == 0) wsum[tid >> 6] = cnt;
    __syncthreads();
    if (tid == 0) flag[0] = (wsum[0] + wsum[1] + wsum[2] + wsum[3] > 100) ? 1 : 0;
}

// ---------- phase A: coarse counting sort by col>>8, clustered writes ----------

__global__ __launch_bounds__(256) void phaseA_kernel(const int* __restrict__ ei,
                                                     int* __restrict__ ccnt,
                                                     u32* __restrict__ cpad) {
    __shared__ int hist[256], lstart[256], lofs[256], gbase[256];
    __shared__ u32 srt[ACH];
    int tid = threadIdx.x;
    int e0 = blockIdx.x * ACH;
    int nv = EE - e0; if (nv > ACH) nv = ACH;
    hist[tid] = 0;
    __syncthreads();
    u32 pk[16];
    int bn[16];
    #pragma unroll
    for (int i = 0; i < 16; i++) {
        int e = e0 + tid + i * 256;
        bn[i] = -1;
        if (e < EE) {
            int r = ei[e], c = ei[EE + e];
            bn[i] = c >> 8;
            pk[i] = (u32)r | ((u32)(c & 255) << 16) | ((u32)bn[i] << 24);
            atomicAdd(&hist[bn[i]], 1);
        }
    }
    __syncthreads();
    int v = hist[tid];
    int excl = excl_scan256(v, tid);
    lstart[tid] = excl;
    lofs[tid] = excl;
    gbase[tid] = atomicAdd(&ccnt[tid], v);
    __syncthreads();
    #pragma unroll
    for (int i = 0; i < 16; i++)
        if (bn[i] >= 0) {
            int lp = atomicAdd(&lofs[bn[i]], 1);
            srt[lp] = pk[i];
        }
    __syncthreads();
    for (int j = tid; j < nv; j += 256) {
        u32 pv = srt[j];
        int b = pv >> 24;
        cpad[(size_t)b * CAP + gbase[b] + (j - lstart[b])] = pv;
    }
}

// exclusive scan of coarse counts -> cbase; sentinels
__global__ void cscan_kernel(const int* __restrict__ ccnt, int* __restrict__ cbase,
                             int* __restrict__ rowptr, float* __restrict__ dinv) {
    int tid = threadIdx.x;
    int v = ccnt[tid];
    int excl = excl_scan256(v, tid);
    cbase[tid] = excl;
    if (tid == 0) {
        rowptr[NN] = EE;
        rowptr[NN + 1] = EE;
        dinv[NN] = 0.f;
    }
}

// ---------- phase B: exact sort within coarse bucket; emits CSR + dinv + rinv ----------

__global__ __launch_bounds__(256) void phaseB_kernel(const u32* __restrict__ cpad,
                                                     const int* __restrict__ ccnt,
                                                     const int* __restrict__ cbase,
                                                     u16* __restrict__ esrc,
                                                     int* __restrict__ rowptr,
                                                     float* __restrict__ dinv,
                                                     float* __restrict__ rinv) {
    __shared__ int hist[256], lstart[256], lofs[256];
    __shared__ u16 srt[CAP];
    int tid = threadIdx.x, cb = blockIdx.x;
    int cnt = ccnt[cb], base = cbase[cb];
    hist[tid] = 0;
    __syncthreads();
    for (int j = tid; j < cnt; j += 256)
        atomicAdd(&hist[(cpad[(size_t)cb * CAP + j] >> 16) & 255], 1);
    __syncthreads();
    int v = hist[tid];
    int excl = excl_scan256(v, tid);
    lstart[tid] = excl;
    lofs[tid] = excl;
    int g = cb * 256 + tid;
    if (g < NN) {
        rowptr[g] = base + excl;
        dinv[g] = v > 0 ? rsqrtf((float)v) : 0.f;
        rinv[g] = v > 0 ? sqrtf((float)v) : 0.f;
    }
    __syncthreads();
    for (int j = tid; j < cnt; j += 256) {
        u32 pv = cpad[(size_t)cb * CAP + j];
        int lp = atomicAdd(&lofs[(pv >> 16) & 255], 1);
        srt[lp] = (u16)(pv & 0xFFFF);
    }
    __syncthreads();
    for (int j = tid; j < cnt; j += 256) esrc[base + j] = srt[j];
}

// ---------- weight prep ----------
// mode 0: chunk J = (k*16 + in/8)*fout + o       (K-concat, ncol=fout)
// mode 1: chunk J = (in/8)*(nk*fout) + k*fout + o (col-concat, ncol=nk*fout)
__global__ void wprep_kernel(const void* __restrict__ w, u16* __restrict__ wt,
                             int fout, int nk, int mode, int total,
                             const int* __restrict__ flag) {
    int idx = blockIdx.x * 256 + threadIdx.x;
    if (idx >= total) return;
    u16 v = flag[0] ? (u16)f2bf(((const float*)w)[idx]) : ((const u16*)w)[idx];
    int per = 128 * fout;
    int k = idx / per, rem = idx % per;
    int in = rem / fout, o = rem % fout;
    size_t J;
    if (mode == 0) J = (size_t)(k * 16 + (in >> 3)) * fout + o;
    else J = (size_t)(in >> 3) * (nk * fout) + k * fout + o;
    wt[J * 8 + (in & 7)] = v;
}

__global__ void bprep_kernel(const void* __restrict__ b1, const void* __restrict__ b2,
                             float* __restrict__ bf, const int* __restrict__ flag) {
    int i = threadIdx.x;  // 192 threads
    if (i < 128) bf[i] = flag[0] ? ((const float*)b1)[i] : bf1(((const u16*)b1)[i]);
    else {
        int j = i - 128;
        bf[i] = flag[0] ? ((const float*)b2)[j] : bf1(((const u16*)b2)[j]);
    }
}

// ---------- scale_x: g0 = dinv .* x (bf16); xb = bf16(x) when f32; zero row NN ----------

__global__ void scalex_kernel(const void* __restrict__ x, u32* __restrict__ g0,
                              u32* __restrict__ xb, const float* __restrict__ dinv,
                              const int* __restrict__ flag) {
    int i = blockIdx.x * 256 + threadIdx.x;
    if (i >= (NN + 1) * 64) return;
    int node = i >> 6;
    int fl = flag[0];
    if (node == NN) {
        g0[i] = 0;
        if (fl) xb[i] = 0;
        return;
    }
    float dv = dinv[node];
    float a, b;
    if (fl) {
        const float* xf = (const float*)x;
        a = xf[2 * i];
        b = xf[2 * i + 1];
        xb[i] = pack2(a, b);
    } else {
        u32 u = ((const u32*)x)[i];
        a = bflo(u);
        b = bfhi(u);
    }
    g0[i] = pack2(a * dv, b * dv);
}

// ---------- propg: g_{k+1} = dinv^2 .* S(g_k), unweighted gather, 128-wide ----------

__global__ __launch_bounds__(256) void propg_kernel(const u32* __restrict__ gin,
                                                    u32* __restrict__ gout,
                                                    const int* __restrict__ rowptr,
                                                    const u16* __restrict__ esrc,
                                                    const float* __restrict__ dinv) {
    int node = (blockIdx.x * 256 + threadIdx.x) >> 6;
    int lane = threadIdx.x & 63;
    if (node > NN) return;
    int e0 = rowptr[node], e1 = rowptr[node + 1];
    float ax = 0.f, ay = 0.f;
    for (int base = e0; base < e1; base += 64) {
        int s_l = NN;  // zero row
        if (base + lane < e1) s_l = esrc[base + lane];
        int cnt = e1 - base;
        if (cnt > 64) cnt = 64;
        for (int j = 0; j < cnt; j += 16) {
            u32 hv[16];
            #pragma unroll
            for (int u = 0; u < 16; u++) {
                int s = __builtin_amdgcn_readlane(s_l, j + u);
                hv[u] = gin[(size_t)s * 64 + lane];
            }
            #pragma unroll
            for (int u = 0; u < 16; u++) {
                ax += bflo(hv[u]);
                ay += bfhi(hv[u]);
            }
        }
    }
    float d = dinv[node];
    float d2 = d * d;
    gout[(size_t)node * 64 + lane] = pack2(ax * d2, ay * d2);
}

// ---------- prop64 (Horner, scaled domain): u_out = dinv.*z + dinv^2.*S(u_in) ----------

__device__ __forceinline__ float gatheru(const u16* __restrict__ uin, int e0, int e1,
                                         int lane, const u16* __restrict__ esrc) {
    float a = 0.f;
    for (int base = e0; base < e1; base += 64) {
        int s_l = NN;
        if (base + lane < e1) s_l = esrc[base + lane];
        int cnt = e1 - base;
        if (cnt > 64) cnt = 64;
        for (int j = 0; j < cnt; j += 16) {
            float hv[16];
            #pragma unroll
            for (int u = 0; u < 16; u++) {
                int s = __builtin_amdgcn_readlane(s_l, j + u);
                hv[u] = bf1(uin[(size_t)s * 64 + lane]);
            }
            #pragma unroll
            for (int u = 0; u < 16; u++) a += hv[u];
        }
    }
    return a;
}

__global__ __launch_bounds__(256) void prop64_add_kernel(const u16* __restrict__ uin,
                                                         const u16* __restrict__ zadd,
                                                         u16* __restrict__ uout,
                                                         const int* __restrict__ rowptr,
                                                         const u16* __restrict__ esrc,
                                                         const float* __restrict__ dinv) {
    int node = (blockIdx.x * 256 + threadIdx.x) >> 6;
    int lane = threadIdx.x & 63;
    if (node > NN) return;
    float s = gatheru(uin, rowptr[node], rowptr[node + 1], lane, esrc);
    float d = dinv[node];
    float r = fmaf(d * d, s, d * bf1(zadd[(size_t)node * 64 + lane]));
    uout[(size_t)node * 64 + lane] = (u16)f2bf(r);
}

__global__ __launch_bounds__(256) void prop64_final_kernel(const u16* __restrict__ uin,
                                                           const u16* __restrict__ z0,
                                                           const float* __restrict__ bias,
                                                           void* __restrict__ outv,
                                                           const int* __restrict__ rowptr,
                                                           const u16* __restrict__ esrc,
                                                           const float* __restrict__ dinv,
                                                           const int* __restrict__ flag) {
    int node = (blockIdx.x * 256 + threadIdx.x) >> 6;
    int lane = threadIdx.x & 63;
    if (node >= NN) return;
    float sg = gatheru(uin, rowptr[node], rowptr[node + 1], lane, esrc);
    float v = dinv[node] * sg + bf1(z0[(size_t)node * 64 + lane]) + bias[lane];
    float m = v;
    #pragma unroll
    for (int off = 32; off; off >>= 1) m = fmaxf(m, __shfl_xor(m, off, 64));
    float e = __expf(v - m);
    float s = e;
    #pragma unroll
    for (int off = 32; off; off >>= 1) s += __shfl_xor(s, off, 64);
    float r = v - m - __logf(s);
    if (flag[0]) ((float*)outv)[(size_t)node * 64 + lane] = r;
    else ((u16*)outv)[(size_t)node * 64 + lane] = (u16)f2bf(r);
}

// ---------- MFMA GEMMs ----------

__device__ __forceinline__ short8 ld8(const u16* p) {
    return __builtin_bit_cast(short8, *(const uint4*)p);
}

// layer 1: H = relu(x@W0 + rinv*(g1@W1+g2@W2+g3@W3) + b1) -> bf16 [N,128].
// 32-row tiles: wave w -> rows rw=16*(w&1), cols cb=64*(w>>1). In-place OK
// (all A-reads are block-local rows, done before epilogue stores).
__global__ __launch_bounds__(256) void gemm1_kernel(const u32* __restrict__ a0,
                                                    const u32* __restrict__ a0alt,
                                                    const u32* __restrict__ a1,
                                                    const u32* __restrict__ a2,
                                                    const u32* __restrict__ a3,
                                                    const u16* __restrict__ wt,
                                                    const float* __restrict__ rinv,
                                                    const float* __restrict__ bias,
                                                    u32* __restrict__ outH,
                                                    const int* __restrict__ flag) {
    __shared__ u32 lds32[2176];  // 8704 B: A-staging (8192 B) / epilogue 32x68
    uint4* hs4 = (uint4*)lds32;
    const u32* A0 = flag[0] ? a0alt : a0;
    const u32* bufs[4] = {A0, a1, a2, a3};
    int t = threadIdx.x;
    int lane = t & 63, w = t >> 6;
    int row0 = blockIdx.x * 32;
    int rw = (w & 1) * 16;   // row half
    int cb = (w >> 1) * 64;  // col half
    int m = lane & 15, qo = lane >> 4;
    f32x4 accx[4], accg[4];
    #pragma unroll
    for (int tt = 0; tt < 4; tt++) {
        accx[tt] = (f32x4){0.f, 0.f, 0.f, 0.f};
        accg[tt] = (f32x4){0.f, 0.f, 0.f, 0.f};
    }
    uint4 p[2];
    {
        const uint4* src = (const uint4*)A0 + (size_t)row0 * 16;
        #pragma unroll
        for (int i = 0; i < 2; i++) p[i] = src[t + 256 * i];
    }
    #pragma unroll
    for (int hop = 0; hop < 4; hop++) {
        __syncthreads();
        #pragma unroll
        for (int i = 0; i < 2; i++) {
            int g = t + 256 * i;
            hs4[(g >> 4) * 16 + ((g & 15) ^ ((g >> 4) & 15))] = p[i];
        }
        __syncthreads();
        if (hop + 1 < 4) {
            const uint4* src = (const uint4*)bufs[hop + 1] + (size_t)row0 * 16;
            #pragma unroll
            for (int i = 0; i < 2; i++) p[i] = src[t + 256 * i];
        }
        #pragma unroll
        for (int q = 0; q < 4; q++) {
            short8 a = __builtin_bit_cast(short8,
                hs4[(rw + m) * 16 + ((q * 4 + qo) ^ m)]);
            short8 b[4];
            #pragma unroll
            for (int tt = 0; tt < 4; tt++)
                b[tt] = ld8(wt + ((size_t)(hop * 16 + q * 4 + qo) * 128 + cb + 16 * tt + m) * 8);
            if (hop == 0) {
                #pragma unroll
                for (int tt = 0; tt < 4; tt++)
                    accx[tt] = __builtin_amdgcn_mfma_f32_16x16x32_bf16(a, b[tt], accx[tt], 0, 0, 0);
            } else {
                #pragma unroll
                for (int tt = 0; tt < 4; tt++)
                    accg[tt] = __builtin_amdgcn_mfma_f32_16x16x32_bf16(a, b[tt], accg[tt], 0, 0, 0);
            }
        }
    }
    int r0 = row0 + rw + qo * 4;
    float rv[4];
    #pragma unroll
    for (int r = 0; r < 4; r++) rv[r] = (r0 + r < NN) ? rinv[r0 + r] : 0.f;
    __syncthreads();  // A-staging reads done; reuse LDS for epilogue
    #pragma unroll
    for (int tt = 0; tt < 4; tt++) {
        float bs = bias[cb + 16 * tt + m];
        #pragma unroll
        for (int r = 0; r < 4; r++) {
            int rr = r0 + r;
            float vv = 0.f;
            if (rr < NN) vv = fmaxf(accx[tt][r] + rv[r] * accg[tt][r] + bs, 0.f);
            u32 vb = f2bf(vv);
            u32 ob = (u32)__shfl_xor((int)vb, 1, 64);
            if (!(m & 1))
                lds32[(rw + qo * 4 + r) * 68 + (cb >> 1) + 8 * tt + (m >> 1)] = vb | (ob << 16);
        }
    }
    __syncthreads();
    uint4* out4 = (uint4*)outH;  // output row = 128 u16 = 16 uint4
    #pragma unroll
    for (int i = 0; i < 2; i++) {
        int g = t + 256 * i;
        int row = g >> 4, ch = g & 15;
        out4[(size_t)(row0 + row) * 16 + ch] = *(const uint4*)&lds32[row * 68 + ch * 4];
    }
}

// layer 2: Z planes = H @ [W2_0|W2_1|W2_2|W2_3]; plane 3 dinv-scaled, row NN zeroed.
// Conflict-free LDS epilogue (stride 36 words).
__global__ __launch_bounds__(256) void gemmz_kernel(const u32* __restrict__ aH,
                                                    const u16* __restrict__ wt,
                                                    const float* __restrict__ dinv,
                                                    u16* __restrict__ p0, u16* __restrict__ p1,
                                                    u16* __restrict__ p2, u16* __restrict__ p3) {
    __shared__ uint4 hs[1024];
    int t = threadIdx.x;
    int lane = t & 63, w = t >> 6;
    int row0 = blockIdx.x * 64;
    int py = blockIdx.y;
    int cb = py * 64;
    int m = lane & 15, qo = lane >> 4;
    f32x4 acc[4];
    #pragma unroll
    for (int tt = 0; tt < 4; tt++) acc[tt] = (f32x4){0.f, 0.f, 0.f, 0.f};
    {
        const uint4* src = (const uint4*)aH + (size_t)row0 * 16;
        #pragma unroll
        for (int i = 0; i < 4; i++) {
            int g = t + 256 * i;
            hs[(g >> 4) * 16 + ((g & 15) ^ ((g >> 4) & 15))] = src[g];
        }
    }
    __syncthreads();
    #pragma unroll
    for (int q = 0; q < 4; q++) {
        short8 a = __builtin_bit_cast(short8,
            hs[(16 * w + m) * 16 + ((q * 4 + qo) ^ m)]);
        short8 b[4];
        #pragma unroll
        for (int tt = 0; tt < 4; tt++)
            b[tt] = ld8(wt + ((size_t)(q * 4 + qo) * 256 + cb + 16 * tt + m) * 8);
        #pragma unroll
        for (int tt = 0; tt < 4; tt++)
            acc[tt] = __builtin_amdgcn_mfma_f32_16x16x32_bf16(a, b[tt], acc[tt], 0, 0, 0);
    }
    u16* zp = (py == 0) ? p0 : (py == 1) ? p1 : (py == 2) ? p2 : p3;
    int r0 = row0 + 16 * w + qo * 4;
    float sc[4];
    #pragma unroll
    for (int r = 0; r < 4; r++) {
        int rr = r0 + r;
        sc[r] = (rr < NN) ? ((py == 3) ? dinv[rr] : 1.f) : 0.f;
    }
    __syncthreads();
    u32* lds32 = (u32*)hs;
    int lrowb = 16 * w + qo * 4;
    #pragma unroll
    for (int tt = 0; tt < 4; tt++) {
        #pragma unroll
        for (int r = 0; r < 4; r++) {
            u32 vb = f2bf(sc[r] * acc[tt][r]);
            u32 ob = (u32)__shfl_xor((int)vb, 1, 64);
            if (!(m & 1))
                lds32[(lrowb + r) * 36 + 8 * tt + (m >> 1)] = vb | (ob << 16);
        }
    }
    __syncthreads();
    uint4* zp4 = (uint4*)zp;  // plane row = 64 u16 = 8 uint4
    #pragma unroll
    for (int i = 0; i < 2; i++) {
        int g = t + 256 * i;
        int row = g >> 3, ch = g & 7;
        zp4[(size_t)(row0 + row) * 8 + ch] = *(const uint4*)&lds32[row * 36 + ch * 4];
    }
}

// ---------- launch ----------

extern "C" void kernel_launch(void* const* d_in, const int* in_sizes, int n_in,
                              void* d_out, int out_size, void* d_ws, size_t ws_size,
                              hipStream_t stream) {
    const void* x  = d_in[0];
    const int*  ei = (const int*)d_in[1];
    const void* W1 = d_in[2];
    const void* b1 = d_in[3];
    const void* W2 = d_in[4];
    const void* b2 = d_in[5];

    char* ws = (char*)d_ws;
    size_t p = 0;
    auto alloc = [&](size_t bytes) -> void* {
        void* r = ws + p;
        p = (p + bytes + 255) & ~(size_t)255;
        return r;
    };
    int*   flag   = (int*)  alloc(256);
    int*   rowptr = (int*)  alloc((size_t)(NN + 2) * 4);
    float* dinv   = (float*)alloc((size_t)(NN + 64) * 4);
    float* rinv   = (float*)alloc((size_t)(NN + 64) * 4);
    int*   ccnt   = (int*)  alloc(256 * 4);
    int*   cbase  = (int*)  alloc(256 * 4);
    u16*   esrc   = (u16*)  alloc((size_t)EE * 2);
    u16*   wt1    = (u16*)  alloc((size_t)64 * 128 * 16);   // 128 KB
    u16*   wt2    = (u16*)  alloc((size_t)16 * 256 * 16);   // 64 KB
    float* biasF  = (float*)alloc(192 * 4);
    const size_t hbytes = (size_t)(NROWS + 16) * 64 * 4;
    u32* X = (u32*)alloc(hbytes);   // xb (flag=1); cpad aliases; Horner scratch
    u32* P = (u32*)alloc(hbytes);   // g0 -> g3 -> z2/u3 planes
    u32* Q = (u32*)alloc(hbytes);   // g1 -> H (in-place)
    u32* R = (u32*)alloc(hbytes);   // g2 -> z0/z1 planes
    // total ~= 53.6 MB
    u32* cpad = X;

    const size_t ZP = (size_t)(NROWS + 16) * 64;  // u16 elements per plane
    u16* zR0 = (u16*)R;        // z0 (R dead after gemm1)
    u16* zR1 = (u16*)R + ZP;   // z1
    u16* zP0 = (u16*)P;        // z2 (later u_w2)
    u16* zP1 = (u16*)P + ZP;   // u3 = dinv.*z3
    u16* uX0 = (u16*)X;        // u_w1

    hipMemsetAsync(ccnt, 0, 256 * 4, stream);
    detect_kernel<<<1, 256, 0, stream>>>((const u32*)x, flag);
    phaseA_kernel<<<(EE + ACH - 1) / ACH, 256, 0, stream>>>(ei, ccnt, cpad);
    cscan_kernel<<<1, 256, 0, stream>>>(ccnt, cbase, rowptr, dinv);
    phaseB_kernel<<<CB, 256, 0, stream>>>(cpad, ccnt, cbase, esrc, rowptr, dinv, rinv);
    wprep_kernel<<<(4 * 128 * 128 + 255) / 256, 256, 0, stream>>>(
        W1, wt1, 128, 4, 0, 4 * 128 * 128, flag);
    wprep_kernel<<<(4 * 128 * 64 + 255) / 256, 256, 0, stream>>>(
        W2, wt2, 64, 4, 1, 4 * 128 * 64, flag);
    bprep_kernel<<<1, 192, 0, stream>>>(b1, b2, biasF, flag);

    const int PGX = ((NN + 1) * 64 + 255) / 256;  // 12501 (covers zero row NN)
    const int PGF = (NN * 64) / 256;              // 12500
    const int GG32 = NROWS / 32;                  // 1564
    const int GG64 = NROWS / 64;                  // 782

    scalex_kernel<<<PGX, 256, 0, stream>>>(x, P, X, dinv, flag);

    // layer 1: g_k chain (unweighted gathers), dual-acc GEMM + bias + relu -> H (=Q)
    propg_kernel<<<PGX, 256, 0, stream>>>(P, Q, rowptr, esrc, dinv);  // g1
    propg_kernel<<<PGX, 256, 0, stream>>>(Q, R, rowptr, esrc, dinv);  // g2
    propg_kernel<<<PGX, 256, 0, stream>>>(R, P, rowptr, esrc, dinv);  // g3 (g0 dead)
    gemm1_kernel<<<GG32, 256, 0, stream>>>(
        (const u32*)x, X, Q, R, P, wt1, rinv, biasF, Q, flag);

    // layer 2: Z planes from H; Horner in scaled domain; fused bias + log_softmax
    gemmz_kernel<<<dim3(GG64, 4), 256, 0, stream>>>(Q, wt2, dinv, zR0, zR1, zP0, zP1);
    prop64_add_kernel<<<PGX, 256, 0, stream>>>(zP1, zP0, uX0, rowptr, esrc, dinv);   // u_w1
    prop64_add_kernel<<<PGX, 256, 0, stream>>>(uX0, zR1, zP0, rowptr, esrc, dinv);   // u_w2
    prop64_final_kernel<<<PGF, 256, 0, stream>>>(zP0, zR0, biasF + 128, d_out,
                                                 rowptr, esrc, dinv, flag);
}